// Round 1
// baseline (994.855 us; speedup 1.0000x reference)
//
#include <hip/hip_runtime.h>

#define BB 16
#define MM 32
#define LH 128
#define NSTEPS 15          // K-1
#define NPX (BB*MM*MM)     // 16384
#define G4 (4*LH)          // 512

__device__ __forceinline__ float sigm(float x){ return 1.f/(1.f+__expf(-x)); }
__device__ __forceinline__ float tanh_f(float x){ return 1.f - 2.f/(__expf(2.f*x)+1.f); }

// W_hh (512,128) -> Wt (128,512)
__global__ __launch_bounds__(256) void k_transpose(const float* __restrict__ whh,
                                                   float* __restrict__ wt){
  int i = blockIdx.x*256 + threadIdx.x;   // 65536 outputs
  int c = i >> 9, r = i & 511;
  wt[i] = whh[r*LH + c];
}

// hid = conv3x3([map,goal], W_hid) + b  -> NHWC (B,32,32,128)
__global__ __launch_bounds__(256) void k_hid(const float* __restrict__ mp,
    const float* __restrict__ gl, const float* __restrict__ W,
    const float* __restrict__ bias, float* __restrict__ hid){
  int p  = blockIdx.x*2 + (threadIdx.x >> 7);
  int ch = threadIdx.x & 127;
  int b = p >> 10, y = (p >> 5) & 31, x = p & 31;
  float acc = bias[ch];
  #pragma unroll
  for (int ky=0; ky<3; ky++){
    int yy = y + ky - 1; if (yy < 0 || yy >= MM) continue;
    #pragma unroll
    for (int kx=0; kx<3; kx++){
      int xx = x + kx - 1; if (xx < 0 || xx >= MM) continue;
      int gi = (b*MM + yy)*MM + xx;
      int wb = ((ky*3+kx)*2)*LH + ch;
      acc += mp[gi] * W[wb] + gl[gi] * W[wb + LH];
    }
  }
  hid[p*LH + ch] = acc;
}

// out = conv3x3(in, W[3,3,128,128]) + b ; one block per (b,y) row
__global__ __launch_bounds__(256) void k_conv128(const float* __restrict__ in,
    const float* __restrict__ W, const float* __restrict__ bias,
    float* __restrict__ out){
  __shared__ float sIn[3][34*LH];   // halo-padded columns 0 and 33
  int row = blockIdx.x;             // b*32 + y
  int b = row >> 5, y = row & 31;
  int t = threadIdx.x;

  #pragma unroll
  for (int ky=0; ky<3; ky++){
    int yy = y + ky - 1;
    if (yy >= 0 && yy < MM){
      const float4* src = (const float4*)(in + ((size_t)(b*MM+yy)*MM)*LH);
      #pragma unroll
      for (int r=0;r<4;r++){
        int fi = r*256 + t;          // 0..1023
        int px = fi >> 5, c4 = fi & 31;
        ((float4*)&sIn[ky][(px+1)*LH])[c4] = src[fi];
      }
    } else {
      #pragma unroll
      for (int r=0;r<4;r++){
        int fi = r*256 + t;
        int px = fi >> 5, c4 = fi & 31;
        ((float4*)&sIn[ky][(px+1)*LH])[c4] = make_float4(0.f,0.f,0.f,0.f);
      }
    }
  }
  if (t < 192){ // zero pad columns: 3 rows x 2 cols x 32 f4
    int ky = t / 64; int rem = t & 63; int col = (rem >> 5) ? 33 : 0; int c4 = rem & 31;
    ((float4*)&sIn[ky][col*LH])[c4] = make_float4(0.f,0.f,0.f,0.f);
  }
  __syncthreads();

  int pg = t >> 5, jg = t & 31;
  int pxb = pg*4, chb = jg*4;
  float4 bv = *(const float4*)(bias + chb);
  float acc[4][4];
  #pragma unroll
  for (int i=0;i<4;i++){ acc[i][0]=bv.x; acc[i][1]=bv.y; acc[i][2]=bv.z; acc[i][3]=bv.w; }

  #pragma unroll
  for (int kk=0; kk<9; kk++){
    int ky = kk/3, kx = kk%3;
    const float4* wrow4 = (const float4*)(W + kk*LH*LH + chb);
    const float* base = &sIn[ky][(pxb + kx)*LH];
    for (int c=0;c<LH;c++){
      float4 w = wrow4[c*(LH/4)];
      float a0 = base[c], a1 = base[LH+c], a2 = base[2*LH+c], a3 = base[3*LH+c];
      acc[0][0]+=a0*w.x; acc[0][1]+=a0*w.y; acc[0][2]+=a0*w.z; acc[0][3]+=a0*w.w;
      acc[1][0]+=a1*w.x; acc[1][1]+=a1*w.y; acc[1][2]+=a1*w.z; acc[1][3]+=a1*w.w;
      acc[2][0]+=a2*w.x; acc[2][1]+=a2*w.y; acc[2][2]+=a2*w.z; acc[2][3]+=a2*w.w;
      acc[3][0]+=a3*w.x; acc[3][1]+=a3*w.y; acc[3][2]+=a3*w.z; acc[3][3]+=a3*w.w;
    }
  }
  #pragma unroll
  for (int i=0;i<4;i++){
    *(float4*)(out + (size_t)(row*MM + pxb + i)*LH + chb) =
      make_float4(acc[i][0],acc[i][1],acc[i][2],acc[i][3]);
  }
}

// inp[p] = conv3x3(h, W_f[3,3,128,1]) + b_f ; one wave per pixel
__global__ __launch_bounds__(256) void k_wf(const float* __restrict__ h,
    const float* __restrict__ Wf, const float* __restrict__ bf,
    float* __restrict__ inp){
  int p = blockIdx.x*4 + (threadIdx.x >> 6);
  int l = threadIdx.x & 63;
  int b = p >> 10, y = (p>>5)&31, x = p & 31;
  float acc = 0.f;
  #pragma unroll
  for (int ky=0; ky<3; ky++){
    int yy = y+ky-1; if (yy<0||yy>=MM) continue;
    #pragma unroll
    for (int kx=0;kx<3;kx++){
      int xx = x+kx-1; if (xx<0||xx>=MM) continue;
      float2 hv = *(const float2*)(h + ((size_t)((b*MM+yy)*MM+xx))*LH + l*2);
      float2 wv = *(const float2*)(Wf + (ky*3+kx)*LH + l*2);
      acc += hv.x*wv.x + hv.y*wv.y;
    }
  }
  #pragma unroll
  for (int s=32; s>0; s>>=1) acc += __shfl_xor(acc, s, 64);
  if (l==0) inp[p] = acc + bf[0];
}

// fused gates GEMM + LSTM pointwise. Block = 32 px x 512 gates.
__global__ __launch_bounds__(256) void k_step(const float* __restrict__ hold,
    const float* __restrict__ wt,     // (128,512) = W_hh^T
    const float* __restrict__ wih, const float* __restrict__ bih,
    const float* __restrict__ bhh, const float* __restrict__ inp,
    float* __restrict__ cbuf, float* __restrict__ hnew){
  __shared__ float sA[32*LH];     // 16 KB
  __shared__ float sB[16*G4];     // 32 KB
  __shared__ float sInp[32];
  int t = threadIdx.x;
  int p0 = blockIdx.x * 32;
  {
    const float4* src = (const float4*)(hold + (size_t)p0*LH);
    float4* dst = (float4*)sA;
    #pragma unroll
    for (int r=0;r<4;r++) dst[r*256 + t] = src[r*256 + t];
    if (t < 32) sInp[t] = inp[p0 + t];
  }
  __syncthreads();
  int pg = t >> 5, jg = t & 31;
  int pxb = pg*4, jb = jg*4;

  float acc[4][4][4]; // [px i][gate q][jj]
  #pragma unroll
  for (int q=0;q<4;q++){
    int rb = q*LH + jb;
    float4 wv = *(const float4*)(wih + rb);
    float4 b1 = *(const float4*)(bih + rb);
    float4 b2 = *(const float4*)(bhh + rb);
    float bw[4] = {b1.x+b2.x, b1.y+b2.y, b1.z+b2.z, b1.w+b2.w};
    float ww[4] = {wv.x, wv.y, wv.z, wv.w};
    #pragma unroll
    for (int i=0;i<4;i++){
      float iv = sInp[pxb+i];
      #pragma unroll
      for (int jj=0;jj<4;jj++) acc[i][q][jj] = iv*ww[jj] + bw[jj];
    }
  }

  for (int kk=0; kk<8; kk++){
    __syncthreads();
    {
      const float4* src = (const float4*)(wt + (size_t)kk*16*G4);
      float4* dst = (float4*)sB;
      #pragma unroll
      for (int r=0;r<8;r++) dst[r*256 + t] = src[r*256 + t];
    }
    __syncthreads();
    const float* sa = sA + pxb*LH + kk*16;
    #pragma unroll
    for (int c2=0;c2<16;c2++){
      float av[4];
      #pragma unroll
      for (int i=0;i<4;i++) av[i] = sa[i*LH + c2];
      const float* sb = sB + c2*G4 + jb;
      float wq[4][4];
      *(float4*)wq[0] = *(const float4*)(sb);
      *(float4*)wq[1] = *(const float4*)(sb + LH);
      *(float4*)wq[2] = *(const float4*)(sb + 2*LH);
      *(float4*)wq[3] = *(const float4*)(sb + 3*LH);
      #pragma unroll
      for (int i=0;i<4;i++)
        #pragma unroll
        for (int q=0;q<4;q++)
          #pragma unroll
          for (int jj=0;jj<4;jj++)
            acc[i][q][jj] += av[i]*wq[q][jj];
    }
  }

  #pragma unroll
  for (int i=0;i<4;i++){
    size_t idx = (size_t)(p0 + pxb + i)*LH + jb;
    float4 cold = *(const float4*)(cbuf + idx);
    float cv[4] = {cold.x,cold.y,cold.z,cold.w};
    float cn[4], hn[4];
    #pragma unroll
    for (int jj=0;jj<4;jj++){
      float iv = sigm(acc[i][0][jj]);
      float fv = sigm(acc[i][1][jj]);
      float gv = tanh_f(acc[i][2][jj]);
      float ov = sigm(acc[i][3][jj]);
      float c2v = fv*cv[jj] + iv*gv;
      cn[jj] = c2v;
      hn[jj] = ov * tanh_f(c2v);
    }
    *(float4*)(cbuf+idx) = make_float4(cn[0],cn[1],cn[2],cn[3]);
    *(float4*)(hnew+idx) = make_float4(hn[0],hn[1],hn[2],hn[3]);
  }
}

// logits + softmax ; one wave per pixel
__global__ __launch_bounds__(256) void k_policy(const float* __restrict__ h,
    const float* __restrict__ wpol, float* __restrict__ out){
  int p = blockIdx.x*4 + (threadIdx.x>>6);
  int l = threadIdx.x & 63;
  float la[4] = {0.f,0.f,0.f,0.f};
  const float* hp = h + (size_t)p*LH;
  #pragma unroll
  for (int cc=0; cc<2; cc++){
    int c = l + cc*64;
    float hv = hp[c];
    float4 w = *(const float4*)(wpol + c*4);
    la[0]+=hv*w.x; la[1]+=hv*w.y; la[2]+=hv*w.z; la[3]+=hv*w.w;
  }
  #pragma unroll
  for (int s=32;s>0;s>>=1){
    la[0]+=__shfl_xor(la[0],s,64);
    la[1]+=__shfl_xor(la[1],s,64);
    la[2]+=__shfl_xor(la[2],s,64);
    la[3]+=__shfl_xor(la[3],s,64);
  }
  if (l==0){
    int b = p >> 10, y=(p>>5)&31, x=p&31;
    float m = fmaxf(fmaxf(la[0],la[1]),fmaxf(la[2],la[3]));
    float e[4]; float s=0.f;
    #pragma unroll
    for (int a=0;a<4;a++){ e[a]=__expf(la[a]-m); s+=e[a]; }
    float inv = 1.f/s;
    #pragma unroll
    for (int a=0;a<4;a++){
      int o = ((b*4 + a)*MM + y)*MM + x;
      out[o] = la[a];
      out[65536 + o] = e[a]*inv;
    }
  }
}

extern "C" void kernel_launch(void* const* d_in, const int* in_sizes, int n_in,
                              void* d_out, int out_size, void* d_ws, size_t ws_size,
                              hipStream_t stream){
  const float* mp    = (const float*)d_in[0];
  const float* gl    = (const float*)d_in[1];
  const float* W_hid = (const float*)d_in[2];
  const float* b_hid = (const float*)d_in[3];
  const float* W_h0  = (const float*)d_in[4];
  const float* b_h0  = (const float*)d_in[5];
  const float* W_c0  = (const float*)d_in[6];
  const float* b_c0  = (const float*)d_in[7];
  const float* W_f   = (const float*)d_in[8];
  const float* b_f   = (const float*)d_in[9];
  const float* W_ih  = (const float*)d_in[10];
  const float* b_ih  = (const float*)d_in[11];
  const float* W_hh  = (const float*)d_in[12];
  const float* b_hh  = (const float*)d_in[13];
  const float* W_pol = (const float*)d_in[14];
  float* out = (float*)d_out;

  char* ws = (char*)d_ws;
  float* bufA = (float*)ws;                          // h0 / h ping   (8 MB)
  float* bufB = (float*)(ws + ((size_t)8<<20));      // hid, then h pong (8 MB)
  float* bufC = (float*)(ws + ((size_t)16<<20));     // c (8 MB)
  float* inp  = (float*)(ws + ((size_t)24<<20));     // 64 KB
  float* wt   = (float*)(ws + ((size_t)24<<20) + 65536); // 256 KB

  k_transpose<<<256,256,0,stream>>>(W_hh, wt);
  k_hid<<<NPX/2,256,0,stream>>>(mp, gl, W_hid, b_hid, bufB);
  k_conv128<<<BB*MM,256,0,stream>>>(bufB, W_h0, b_h0, bufA);
  k_conv128<<<BB*MM,256,0,stream>>>(bufB, W_c0, b_c0, bufC);

  float* hc = bufA; float* hn = bufB;
  for (int s=0;s<NSTEPS;s++){
    k_wf<<<NPX/4,256,0,stream>>>(hc, W_f, b_f, inp);
    k_step<<<NPX/32,256,0,stream>>>(hc, wt, W_ih, b_ih, b_hh, inp, bufC, hn);
    float* tmp = hc; hc = hn; hn = tmp;
  }
  k_policy<<<NPX/4,256,0,stream>>>(hc, W_pol, out);
}

// Round 2
// 550.704 us; speedup vs baseline: 1.8065x; 1.8065x over previous
//
#include <hip/hip_runtime.h>

#define BB 16
#define MM 32
#define LH 128
#define NSTEPS 15          // K-1
#define NPX (BB*MM*MM)     // 16384

typedef __bf16  bf16x8  __attribute__((ext_vector_type(8)));
typedef float   floatx4 __attribute__((ext_vector_type(4)));

__device__ __forceinline__ float sigm(float x){ return 1.f/(1.f+__expf(-x)); }
__device__ __forceinline__ float tanh_f(float x){ return 1.f - 2.f/(__expf(2.f*x)+1.f); }

__device__ __forceinline__ unsigned short f2bf(float x){
  union { float f; unsigned u; } v; v.f = x;
  unsigned r = v.u + 0x7FFFu + ((v.u >> 16) & 1u);   // RNE
  return (unsigned short)(r >> 16);
}
__device__ __forceinline__ float bf2f(unsigned short u){
  union { unsigned u; float f; } v; v.u = ((unsigned)u) << 16;
  return v.f;
}

// ---- prep: bf16 weight conversions (+transposes) + bias sum -------------
// wc layout out: (kk, co, ci) bf16 ; whh out: (512,128) bf16 row-major
__global__ __launch_bounds__(256) void k_prep(const float* __restrict__ Wh0,
    const float* __restrict__ Wc0, const float* __restrict__ Whh,
    const float* __restrict__ bih, const float* __restrict__ bhh,
    unsigned short* __restrict__ wc0, unsigned short* __restrict__ wc1,
    unsigned short* __restrict__ whh, float* __restrict__ bsum){
  int id = blockIdx.x*256 + threadIdx.x;
  if (id < 147456){
    int kk = id >> 14, rem = id & 16383, ci = rem >> 7, co = rem & 127;
    wc0[(kk<<14) + co*128 + ci] = f2bf(Wh0[id]);
  } else if (id < 294912){
    int i2 = id - 147456;
    int kk = i2 >> 14, rem = i2 & 16383, ci = rem >> 7, co = rem & 127;
    wc1[(kk<<14) + co*128 + ci] = f2bf(Wc0[i2]);
  } else if (id < 360448){
    int i2 = id - 294912;
    whh[i2] = f2bf(Whh[i2]);
  } else if (id < 360960){
    int j = id - 360448;
    bsum[j] = bih[j] + bhh[j];
  }
}

// ---- hid = conv3x3([map,goal]) + b -> bf16 NHWC -------------------------
__global__ __launch_bounds__(256) void k_hid(const float* __restrict__ mp,
    const float* __restrict__ gl, const float* __restrict__ W,
    const float* __restrict__ bias, unsigned short* __restrict__ hidbf){
  int p  = blockIdx.x*2 + (threadIdx.x >> 7);
  int ch = threadIdx.x & 127;
  int b = p >> 10, y = (p >> 5) & 31, x = p & 31;
  float acc = bias[ch];
  #pragma unroll
  for (int ky=0; ky<3; ky++){
    int yy = y + ky - 1; if (yy < 0 || yy >= MM) continue;
    #pragma unroll
    for (int kx=0; kx<3; kx++){
      int xx = x + kx - 1; if (xx < 0 || xx >= MM) continue;
      int gi = (b*MM + yy)*MM + xx;
      int wb = ((ky*3+kx)*2)*LH + ch;
      acc += mp[gi] * W[wb] + gl[gi] * W[wb + LH];
    }
  }
  hidbf[p*LH + ch] = f2bf(acc);
}

// ---- conv3x3 128->128 via MFMA. One block per (b,y) image row. ----------
// in bf16 NHWC, wc bf16 (kk,co,ci), outF fp32 (may be null), outB bf16 (may be null)
#define SSTR 136
__global__ __launch_bounds__(256) void k_conv_mfma(const unsigned short* __restrict__ inbf,
    const unsigned short* __restrict__ wc, const float* __restrict__ bias,
    float* __restrict__ outF, unsigned short* __restrict__ outB){
  __shared__ unsigned short sIn[3][34*SSTR];
  int row = blockIdx.x;             // b*32 + y
  int b = row >> 5, y = row & 31;
  int t = threadIdx.x;

  int px = t >> 3, ch0 = (t & 7) * 16;
  #pragma unroll
  for (int ky=0; ky<3; ky++){
    int yy = y + ky - 1;
    uint4 v0 = make_uint4(0,0,0,0), v1 = v0;
    if (yy >= 0 && yy < MM){
      const unsigned short* src = inbf + ((size_t)((b*MM+yy)*MM))*LH + t*16;
      v0 = *(const uint4*)(src);
      v1 = *(const uint4*)(src + 8);
    }
    *(uint4*)&sIn[ky][(px+1)*SSTR + ch0]     = v0;
    *(uint4*)&sIn[ky][(px+1)*SSTR + ch0 + 8] = v1;
    if (t < 32){
      int col = (t >> 4) * 33; int c8 = (t & 15) * 8;
      *(uint4*)&sIn[ky][col*SSTR + c8] = make_uint4(0,0,0,0);
    }
  }
  __syncthreads();

  int wave = t >> 6, l = t & 63, m16 = l & 15, quad = l >> 4;
  int cob = wave * 32;

  floatx4 acc[2][2];
  #pragma unroll
  for (int mt=0;mt<2;mt++)
    #pragma unroll
    for (int nt=0;nt<2;nt++) acc[mt][nt] = (floatx4){0.f,0.f,0.f,0.f};

  #pragma unroll
  for (int kk=0; kk<9; kk++){
    int ky = kk/3, kx = kk%3;
    #pragma unroll
    for (int kc=0; kc<4; kc++){
      bf16x8 a0 = *(const bf16x8*)&sIn[ky][(m16      + kx)*SSTR + kc*32 + quad*8];
      bf16x8 a1 = *(const bf16x8*)&sIn[ky][(m16 + 16 + kx)*SSTR + kc*32 + quad*8];
      #pragma unroll
      for (int nt=0; nt<2; nt++){
        int co = cob + nt*16 + m16;
        bf16x8 bf = *(const bf16x8*)(wc + (kk<<14) + co*128 + kc*32 + quad*8);
        acc[0][nt] = __builtin_amdgcn_mfma_f32_16x16x32_bf16(a0, bf, acc[0][nt], 0,0,0);
        acc[1][nt] = __builtin_amdgcn_mfma_f32_16x16x32_bf16(a1, bf, acc[1][nt], 0,0,0);
      }
    }
  }

  #pragma unroll
  for (int nt=0; nt<2; nt++){
    int co = cob + nt*16 + m16;
    float bv = bias[co];
    #pragma unroll
    for (int mt=0; mt<2; mt++){
      #pragma unroll
      for (int r=0; r<4; r++){
        int x = mt*16 + quad*4 + r;
        size_t idx = (size_t)(row*MM + x)*LH + co;
        float v = acc[mt][nt][r] + bv;
        if (outF) outF[idx] = v;
        if (outB) outB[idx] = f2bf(v);
      }
    }
  }
}

// ---- inp = conv3x3(h, W_f) + b_f ; one wave per pixel, h is bf16 --------
__global__ __launch_bounds__(256) void k_wf(const unsigned short* __restrict__ h,
    const float* __restrict__ Wf, const float* __restrict__ bf,
    float* __restrict__ inp){
  int p = blockIdx.x*4 + (threadIdx.x >> 6);
  int l = threadIdx.x & 63;
  int b = p >> 10, y = (p>>5)&31, x = p & 31;
  float acc = 0.f;
  #pragma unroll
  for (int ky=0; ky<3; ky++){
    int yy = y+ky-1; if (yy<0||yy>=MM) continue;
    #pragma unroll
    for (int kx=0;kx<3;kx++){
      int xx = x+kx-1; if (xx<0||xx>=MM) continue;
      const unsigned short* hp = h + ((size_t)((b*MM+yy)*MM+xx))*LH + l*2;
      ushort2 hv = *(const ushort2*)hp;
      float2 wv = *(const float2*)(Wf + (ky*3+kx)*LH + l*2);
      acc += bf2f(hv.x)*wv.x + bf2f(hv.y)*wv.y;
    }
  }
  #pragma unroll
  for (int s=32; s>0; s>>=1) acc += __shfl_xor(acc, s, 64);
  if (l==0) inp[p] = acc + bf[0];
}

// ---- fused gates GEMM (MFMA) + LSTM pointwise ---------------------------
// block: 32 px, 4 waves; wave w owns channels [w*32, w*32+32) for ALL 4 gates
__global__ __launch_bounds__(256) void k_step(const unsigned short* __restrict__ hbfin,
    const unsigned short* __restrict__ whh,   // (512,128) bf16 = B^T
    const float* __restrict__ wih, const float* __restrict__ bsum,
    const float* __restrict__ inp,
    float* __restrict__ cbuf, unsigned short* __restrict__ hbfout){
  __shared__ unsigned short sA[32*SSTR];
  __shared__ float sInp[32];
  int t = threadIdx.x;
  int p0 = blockIdx.x * 32;
  {
    int rr = t >> 3, c0 = (t & 7) * 16;
    const unsigned short* src = hbfin + (size_t)p0*LH + t*16;
    *(uint4*)&sA[rr*SSTR + c0]     = *(const uint4*)(src);
    *(uint4*)&sA[rr*SSTR + c0 + 8] = *(const uint4*)(src + 8);
    if (t < 32) sInp[t] = inp[p0 + t];
  }
  __syncthreads();

  int wave = t >> 6, l = t & 63, m16 = l & 15, quad = l >> 4;
  int chb = wave * 32;

  floatx4 acc[2][4][2];   // [mt][gate q][nt]
  #pragma unroll
  for (int mt=0;mt<2;mt++)
    #pragma unroll
    for (int q=0;q<4;q++)
      #pragma unroll
      for (int nt=0;nt<2;nt++) acc[mt][q][nt] = (floatx4){0.f,0.f,0.f,0.f};

  #pragma unroll
  for (int kc=0; kc<4; kc++){
    bf16x8 a0 = *(const bf16x8*)&sA[(m16     )*SSTR + kc*32 + quad*8];
    bf16x8 a1 = *(const bf16x8*)&sA[(m16 + 16)*SSTR + kc*32 + quad*8];
    #pragma unroll
    for (int q=0; q<4; q++){
      #pragma unroll
      for (int nt=0; nt<2; nt++){
        int gr = q*128 + chb + nt*16 + m16;
        bf16x8 bf = *(const bf16x8*)(whh + (size_t)gr*128 + kc*32 + quad*8);
        acc[0][q][nt] = __builtin_amdgcn_mfma_f32_16x16x32_bf16(a0, bf, acc[0][q][nt], 0,0,0);
        acc[1][q][nt] = __builtin_amdgcn_mfma_f32_16x16x32_bf16(a1, bf, acc[1][q][nt], 0,0,0);
      }
    }
  }

  #pragma unroll
  for (int nt=0; nt<2; nt++){
    int ch = chb + nt*16 + m16;
    float wv[4], bs[4];
    #pragma unroll
    for (int q=0;q<4;q++){ int g = q*128 + ch; wv[q] = wih[g]; bs[q] = bsum[g]; }
    #pragma unroll
    for (int mt=0; mt<2; mt++){
      #pragma unroll
      for (int r=0; r<4; r++){
        int pxl = mt*16 + quad*4 + r;
        float iv = sInp[pxl];
        float pre0 = acc[mt][0][nt][r] + iv*wv[0] + bs[0];
        float pre1 = acc[mt][1][nt][r] + iv*wv[1] + bs[1];
        float pre2 = acc[mt][2][nt][r] + iv*wv[2] + bs[2];
        float pre3 = acc[mt][3][nt][r] + iv*wv[3] + bs[3];
        float ig = sigm(pre0), fg = sigm(pre1), gg = tanh_f(pre2), og = sigm(pre3);
        size_t idx = (size_t)(p0 + pxl)*LH + ch;
        float cold = cbuf[idx];
        float cn = fg*cold + ig*gg;
        cbuf[idx] = cn;
        hbfout[idx] = f2bf(og * tanh_f(cn));
      }
    }
  }
}

// ---- policy: logits + softmax ; one wave per pixel, h bf16 --------------
__global__ __launch_bounds__(256) void k_policy(const unsigned short* __restrict__ h,
    const float* __restrict__ wpol, float* __restrict__ out){
  int p = blockIdx.x*4 + (threadIdx.x>>6);
  int l = threadIdx.x & 63;
  float la[4] = {0.f,0.f,0.f,0.f};
  const unsigned short* hp = h + (size_t)p*LH;
  #pragma unroll
  for (int cc=0; cc<2; cc++){
    int c = l + cc*64;
    float hv = bf2f(hp[c]);
    float4 w = *(const float4*)(wpol + c*4);
    la[0]+=hv*w.x; la[1]+=hv*w.y; la[2]+=hv*w.z; la[3]+=hv*w.w;
  }
  #pragma unroll
  for (int s=32;s>0;s>>=1){
    la[0]+=__shfl_xor(la[0],s,64);
    la[1]+=__shfl_xor(la[1],s,64);
    la[2]+=__shfl_xor(la[2],s,64);
    la[3]+=__shfl_xor(la[3],s,64);
  }
  if (l==0){
    int b = p >> 10, y=(p>>5)&31, x=p&31;
    float m = fmaxf(fmaxf(la[0],la[1]),fmaxf(la[2],la[3]));
    float e[4]; float s=0.f;
    #pragma unroll
    for (int a=0;a<4;a++){ e[a]=__expf(la[a]-m); s+=e[a]; }
    float inv = 1.f/s;
    #pragma unroll
    for (int a=0;a<4;a++){
      int o = ((b*4 + a)*MM + y)*MM + x;
      out[o] = la[a];
      out[65536 + o] = e[a]*inv;
    }
  }
}

extern "C" void kernel_launch(void* const* d_in, const int* in_sizes, int n_in,
                              void* d_out, int out_size, void* d_ws, size_t ws_size,
                              hipStream_t stream){
  const float* mp    = (const float*)d_in[0];
  const float* gl    = (const float*)d_in[1];
  const float* W_hid = (const float*)d_in[2];
  const float* b_hid = (const float*)d_in[3];
  const float* W_h0  = (const float*)d_in[4];
  const float* b_h0  = (const float*)d_in[5];
  const float* W_c0  = (const float*)d_in[6];
  const float* b_c0  = (const float*)d_in[7];
  const float* W_f   = (const float*)d_in[8];
  const float* b_f   = (const float*)d_in[9];
  const float* W_ih  = (const float*)d_in[10];
  const float* b_ih  = (const float*)d_in[11];
  const float* W_hh  = (const float*)d_in[12];
  const float* b_hh  = (const float*)d_in[13];
  const float* W_pol = (const float*)d_in[14];
  float* out = (float*)d_out;

  char* ws = (char*)d_ws;
  float*          cbuf  = (float*)ws;                                   // 8 MB fp32 c
  unsigned short* hbfA  = (unsigned short*)(ws + ((size_t) 8<<20));     // 4 MB bf16 h ping
  unsigned short* hbfB  = (unsigned short*)(ws + ((size_t)12<<20));     // 4 MB bf16 h pong
  unsigned short* hidbf = (unsigned short*)(ws + ((size_t)16<<20));     // 4 MB bf16 hid
  float*          inp   = (float*)(ws + ((size_t)20<<20));              // 64 KB
  unsigned short* whhbf = (unsigned short*)(ws + ((size_t)20<<20) + (64<<10));  // 128 KB
  float*          bsum  = (float*)(ws + ((size_t)20<<20) + (192<<10));  // 4 KB
  unsigned short* wc0bf = (unsigned short*)(ws + ((size_t)20<<20) + (196<<10)); // 288 KB
  unsigned short* wc1bf = (unsigned short*)(ws + ((size_t)20<<20) + (484<<10)); // 288 KB

  k_prep<<<1410,256,0,stream>>>(W_h0, W_c0, W_hh, b_ih, b_hh, wc0bf, wc1bf, whhbf, bsum);
  k_hid<<<NPX/2,256,0,stream>>>(mp, gl, W_hid, b_hid, hidbf);
  k_conv_mfma<<<BB*MM,256,0,stream>>>(hidbf, wc0bf, b_h0, (float*)nullptr, hbfA);
  k_conv_mfma<<<BB*MM,256,0,stream>>>(hidbf, wc1bf, b_c0, cbuf, (unsigned short*)nullptr);

  unsigned short* hc = hbfA; unsigned short* hn = hbfB;
  for (int s=0;s<NSTEPS;s++){
    k_wf<<<NPX/4,256,0,stream>>>(hc, W_f, b_f, inp);
    k_step<<<NPX/32,256,0,stream>>>(hc, whhbf, W_ih, bsum, inp, cbuf, hn);
    unsigned short* tmp = hc; hc = hn; hn = tmp;
  }
  k_policy<<<NPX/4,256,0,stream>>>(hc, W_pol, out);
}

// Round 3
// 436.506 us; speedup vs baseline: 2.2791x; 1.2616x over previous
//
#include <hip/hip_runtime.h>

#define BB 16
#define MM 32
#define LH 128
#define NSTEPS 15          // K-1
#define NPX (BB*MM*MM)     // 16384
#define SSTR 136

typedef __bf16  bf16x8  __attribute__((ext_vector_type(8)));
typedef float   floatx4 __attribute__((ext_vector_type(4)));

__device__ __forceinline__ float sigm(float x){ return 1.f/(1.f+__expf(-x)); }
__device__ __forceinline__ float tanh_f(float x){ return 1.f - 2.f/(__expf(2.f*x)+1.f); }

__device__ __forceinline__ unsigned short f2bf(float x){
  union { float f; unsigned u; } v; v.f = x;
  unsigned r = v.u + 0x7FFFu + ((v.u >> 16) & 1u);   // RNE
  return (unsigned short)(r >> 16);
}
__device__ __forceinline__ float bf2f(unsigned short u){
  union { unsigned u; float f; } v; v.u = ((unsigned)u) << 16;
  return v.f;
}

// ---- prep: bf16 weight conversions into FRAGMENT-LINEAR layouts ---------
// conv frag: id = ((kk*8+ct)*4+kc)*512 + l*8 + e ; holds W[kk][ci][co],
//   co = ct*16 + (l&15), ci = kc*32 + (l>>4)*8 + e
// whh frag: id = ((q*8+ct)*4+kc)*512 + l*8 + e ; holds Whh[row][col],
//   row = q*128 + ct*16 + (l&15), col = kc*32 + (l>>4)*8 + e
__global__ __launch_bounds__(256) void k_prep(const float* __restrict__ Wh0,
    const float* __restrict__ Wc0, const float* __restrict__ Whh,
    const float* __restrict__ bih, const float* __restrict__ bhh,
    unsigned short* __restrict__ wc0, unsigned short* __restrict__ wc1,
    unsigned short* __restrict__ whhf, float* __restrict__ bsum){
  int id = blockIdx.x*256 + threadIdx.x;
  if (id < 294912){
    int i2 = (id < 147456) ? id : id - 147456;
    int frag = i2 >> 9, rem = i2 & 511, l = rem >> 3, e = rem & 7;
    int kk = frag >> 5, ct = (frag >> 2) & 7, kc = frag & 3;
    int co = ct*16 + (l & 15), ci = kc*32 + ((l >> 4) << 3) + e;
    const float* src = (id < 147456) ? Wh0 : Wc0;
    unsigned short* dst = (id < 147456) ? wc0 : wc1;
    dst[i2] = f2bf(src[(kk<<14) + ci*128 + co]);
  } else if (id < 360448){
    int i2 = id - 294912;
    int frag = i2 >> 9, rem = i2 & 511, l = rem >> 3, e = rem & 7;
    int q = frag >> 5, ct = (frag >> 2) & 7, kc = frag & 3;
    int row = q*128 + ct*16 + (l & 15), col = kc*32 + ((l >> 4) << 3) + e;
    whhf[i2] = f2bf(Whh[row*128 + col]);
  } else if (id < 360960){
    int j = id - 360448;
    bsum[j] = bih[j] + bhh[j];
  }
}

// ---- hid = conv3x3([map,goal]) + b -> bf16 NHWC -------------------------
__global__ __launch_bounds__(256) void k_hid(const float* __restrict__ mp,
    const float* __restrict__ gl, const float* __restrict__ W,
    const float* __restrict__ bias, unsigned short* __restrict__ hidbf){
  int p  = blockIdx.x*2 + (threadIdx.x >> 7);
  int ch = threadIdx.x & 127;
  int b = p >> 10, y = (p >> 5) & 31, x = p & 31;
  float acc = bias[ch];
  #pragma unroll
  for (int ky=0; ky<3; ky++){
    int yy = y + ky - 1; if (yy < 0 || yy >= MM) continue;
    #pragma unroll
    for (int kx=0; kx<3; kx++){
      int xx = x + kx - 1; if (xx < 0 || xx >= MM) continue;
      int gi = (b*MM + yy)*MM + xx;
      int wb = ((ky*3+kx)*2)*LH + ch;
      acc += mp[gi] * W[wb] + gl[gi] * W[wb + LH];
    }
  }
  hidbf[p*LH + ch] = f2bf(acc);
}

// ---- conv3x3 128->128 via MFMA. One block per (b,y) image row. ----------
__global__ __launch_bounds__(256) void k_conv_mfma(const unsigned short* __restrict__ inbf,
    const unsigned short* __restrict__ wc, const float* __restrict__ bias,
    float* __restrict__ outF, unsigned short* __restrict__ outB){
  __shared__ unsigned short sIn[3][34*SSTR];
  int row = blockIdx.x;             // b*32 + y
  int b = row >> 5, y = row & 31;
  int t = threadIdx.x;

  int px = t >> 3, ch0 = (t & 7) * 16;
  #pragma unroll
  for (int ky=0; ky<3; ky++){
    int yy = y + ky - 1;
    uint4 v0 = make_uint4(0,0,0,0), v1 = v0;
    if (yy >= 0 && yy < MM){
      const unsigned short* src = inbf + ((size_t)((b*MM+yy)*MM))*LH + t*16;
      v0 = *(const uint4*)(src);
      v1 = *(const uint4*)(src + 8);
    }
    *(uint4*)&sIn[ky][(px+1)*SSTR + ch0]     = v0;
    *(uint4*)&sIn[ky][(px+1)*SSTR + ch0 + 8] = v1;
    if (t < 32){
      int col = (t >> 4) * 33; int c8 = (t & 15) * 8;
      *(uint4*)&sIn[ky][col*SSTR + c8] = make_uint4(0,0,0,0);
    }
  }
  __syncthreads();

  int wave = t >> 6, l = t & 63, m16 = l & 15, quad = l >> 4;

  floatx4 acc[2][2];
  #pragma unroll
  for (int mt=0;mt<2;mt++)
    #pragma unroll
    for (int nt=0;nt<2;nt++) acc[mt][nt] = (floatx4){0.f,0.f,0.f,0.f};

  #pragma unroll
  for (int kk=0; kk<9; kk++){
    int ky = kk/3, kx = kk%3;
    #pragma unroll
    for (int kc=0; kc<4; kc++){
      bf16x8 a0 = *(const bf16x8*)&sIn[ky][(m16      + kx)*SSTR + kc*32 + quad*8];
      bf16x8 a1 = *(const bf16x8*)&sIn[ky][(m16 + 16 + kx)*SSTR + kc*32 + quad*8];
      #pragma unroll
      for (int nt=0; nt<2; nt++){
        int frag = ((kk*8 + (wave*2 + nt))*4 + kc);
        bf16x8 bf = *(const bf16x8*)(wc + (frag << 9) + l*8);
        acc[0][nt] = __builtin_amdgcn_mfma_f32_16x16x32_bf16(a0, bf, acc[0][nt], 0,0,0);
        acc[1][nt] = __builtin_amdgcn_mfma_f32_16x16x32_bf16(a1, bf, acc[1][nt], 0,0,0);
      }
    }
  }

  #pragma unroll
  for (int nt=0; nt<2; nt++){
    int co = wave*32 + nt*16 + m16;
    float bv = bias[co];
    #pragma unroll
    for (int mt=0; mt<2; mt++){
      #pragma unroll
      for (int r=0; r<4; r++){
        int x = mt*16 + quad*4 + r;
        size_t idx = (size_t)(row*MM + x)*LH + co;
        float v = acc[mt][nt][r] + bv;
        if (outF) outF[idx] = v;
        if (outB) outB[idx] = f2bf(v);
      }
    }
  }
}

// ---- fused: wf conv (scalar gate input) + gates GEMM + LSTM pointwise ---
// block = 32 px (one image row), 4 waves; wave w owns ch [w*32,w*32+32) for all 4 gates
__global__ __launch_bounds__(256) void k_step(const unsigned short* __restrict__ hbfin,
    const unsigned short* __restrict__ whh,   // frag-linear (q,ct,kc)
    const float* __restrict__ Wf, const float* __restrict__ bfs,
    const float* __restrict__ wih, const float* __restrict__ bsum,
    float* __restrict__ cbuf, unsigned short* __restrict__ hbfout){
  __shared__ unsigned short sA[32*SSTR];
  __shared__ float sInp[32];
  int t = threadIdx.x;
  int row = blockIdx.x;             // b*32 + y
  int b = row >> 5, y = row & 31;
  int p0 = row * 32;

  // stage A (this row's h) for the GEMM
  {
    int rr = t >> 3, c0 = (t & 7) * 16;
    const unsigned short* src = hbfin + (size_t)p0*LH + t*16;
    *(uint4*)&sA[rr*SSTR + c0]     = *(const uint4*)(src);
    *(uint4*)&sA[rr*SSTR + c0 + 8] = *(const uint4*)(src + 8);
  }

  // wf phase: 8 lanes per pixel, 16 ch each, 9 taps
  {
    int px = t >> 3, s8 = t & 7;
    float a = 0.f;
    #pragma unroll
    for (int ky=0; ky<3; ky++){
      int yy = y + ky - 1; if (yy < 0 || yy >= MM) continue;
      #pragma unroll
      for (int kx=0; kx<3; kx++){
        int xx = px + kx - 1; if (xx < 0 || xx >= MM) continue;
        const unsigned short* hp = hbfin + ((size_t)((b*MM+yy)*MM+xx))*LH + s8*16;
        const float* wp = Wf + (ky*3+kx)*LH + s8*16;
        uint4 h0 = *(const uint4*)hp;
        uint4 h1 = *(const uint4*)(hp + 8);
        const unsigned short* hu = (const unsigned short*)&h0;
        #pragma unroll
        for (int e=0;e<8;e++) a += bf2f(hu[e]) * wp[e];
        hu = (const unsigned short*)&h1;
        #pragma unroll
        for (int e=0;e<8;e++) a += bf2f(hu[e]) * wp[8+e];
      }
    }
    a += __shfl_xor(a, 1, 64);
    a += __shfl_xor(a, 2, 64);
    a += __shfl_xor(a, 4, 64);
    if (s8 == 0) sInp[px] = a + bfs[0];
  }
  __syncthreads();

  int wave = t >> 6, l = t & 63, m16 = l & 15, quad = l >> 4;

  floatx4 acc[2][4][2];   // [mt][gate q][nt]
  #pragma unroll
  for (int mt=0;mt<2;mt++)
    #pragma unroll
    for (int q=0;q<4;q++)
      #pragma unroll
      for (int nt=0;nt<2;nt++) acc[mt][q][nt] = (floatx4){0.f,0.f,0.f,0.f};

  #pragma unroll
  for (int kc=0; kc<4; kc++){
    bf16x8 a0 = *(const bf16x8*)&sA[(m16     )*SSTR + kc*32 + quad*8];
    bf16x8 a1 = *(const bf16x8*)&sA[(m16 + 16)*SSTR + kc*32 + quad*8];
    #pragma unroll
    for (int q=0; q<4; q++){
      #pragma unroll
      for (int nt=0; nt<2; nt++){
        int frag = ((q*8 + (wave*2 + nt))*4 + kc);
        bf16x8 bf = *(const bf16x8*)(whh + (frag << 9) + l*8);
        acc[0][q][nt] = __builtin_amdgcn_mfma_f32_16x16x32_bf16(a0, bf, acc[0][q][nt], 0,0,0);
        acc[1][q][nt] = __builtin_amdgcn_mfma_f32_16x16x32_bf16(a1, bf, acc[1][q][nt], 0,0,0);
      }
    }
  }

  #pragma unroll
  for (int nt=0; nt<2; nt++){
    int ch = wave*32 + nt*16 + m16;
    float wv[4], bs[4];
    #pragma unroll
    for (int q=0;q<4;q++){ int g = q*128 + ch; wv[q] = wih[g]; bs[q] = bsum[g]; }
    #pragma unroll
    for (int mt=0; mt<2; mt++){
      #pragma unroll
      for (int r=0; r<4; r++){
        int pxl = mt*16 + quad*4 + r;
        float iv = sInp[pxl];
        float pre0 = acc[mt][0][nt][r] + iv*wv[0] + bs[0];
        float pre1 = acc[mt][1][nt][r] + iv*wv[1] + bs[1];
        float pre2 = acc[mt][2][nt][r] + iv*wv[2] + bs[2];
        float pre3 = acc[mt][3][nt][r] + iv*wv[3] + bs[3];
        float ig = sigm(pre0), fg = sigm(pre1), gg = tanh_f(pre2), og = sigm(pre3);
        size_t idx = (size_t)(p0 + pxl)*LH + ch;
        float cold = cbuf[idx];
        float cn = fg*cold + ig*gg;
        cbuf[idx] = cn;
        hbfout[idx] = f2bf(og * tanh_f(cn));
      }
    }
  }
}

// ---- policy: logits + softmax ; one wave per pixel, h bf16 --------------
__global__ __launch_bounds__(256) void k_policy(const unsigned short* __restrict__ h,
    const float* __restrict__ wpol, float* __restrict__ out){
  int p = blockIdx.x*4 + (threadIdx.x>>6);
  int l = threadIdx.x & 63;
  float la[4] = {0.f,0.f,0.f,0.f};
  const unsigned short* hp = h + (size_t)p*LH;
  #pragma unroll
  for (int cc=0; cc<2; cc++){
    int c = l + cc*64;
    float hv = bf2f(hp[c]);
    float4 w = *(const float4*)(wpol + c*4);
    la[0]+=hv*w.x; la[1]+=hv*w.y; la[2]+=hv*w.z; la[3]+=hv*w.w;
  }
  #pragma unroll
  for (int s=32;s>0;s>>=1){
    la[0]+=__shfl_xor(la[0],s,64);
    la[1]+=__shfl_xor(la[1],s,64);
    la[2]+=__shfl_xor(la[2],s,64);
    la[3]+=__shfl_xor(la[3],s,64);
  }
  if (l==0){
    int b = p >> 10, y=(p>>5)&31, x=p&31;
    float m = fmaxf(fmaxf(la[0],la[1]),fmaxf(la[2],la[3]));
    float e[4]; float s=0.f;
    #pragma unroll
    for (int a=0;a<4;a++){ e[a]=__expf(la[a]-m); s+=e[a]; }
    float inv = 1.f/s;
    #pragma unroll
    for (int a=0;a<4;a++){
      int o = ((b*4 + a)*MM + y)*MM + x;
      out[o] = la[a];
      out[65536 + o] = e[a]*inv;
    }
  }
}

extern "C" void kernel_launch(void* const* d_in, const int* in_sizes, int n_in,
                              void* d_out, int out_size, void* d_ws, size_t ws_size,
                              hipStream_t stream){
  const float* mp    = (const float*)d_in[0];
  const float* gl    = (const float*)d_in[1];
  const float* W_hid = (const float*)d_in[2];
  const float* b_hid = (const float*)d_in[3];
  const float* W_h0  = (const float*)d_in[4];
  const float* b_h0  = (const float*)d_in[5];
  const float* W_c0  = (const float*)d_in[6];
  const float* b_c0  = (const float*)d_in[7];
  const float* W_f   = (const float*)d_in[8];
  const float* b_f   = (const float*)d_in[9];
  const float* W_ih  = (const float*)d_in[10];
  const float* b_ih  = (const float*)d_in[11];
  const float* W_hh  = (const float*)d_in[12];
  const float* b_hh  = (const float*)d_in[13];
  const float* W_pol = (const float*)d_in[14];
  float* out = (float*)d_out;

  char* ws = (char*)d_ws;
  float*          cbuf  = (float*)ws;                                   // 8 MB fp32 c
  unsigned short* hbfA  = (unsigned short*)(ws + ((size_t) 8<<20));     // 4 MB bf16 h ping
  unsigned short* hbfB  = (unsigned short*)(ws + ((size_t)12<<20));     // 4 MB bf16 h pong
  unsigned short* hidbf = (unsigned short*)(ws + ((size_t)16<<20));     // 4 MB bf16 hid
  unsigned short* whhbf = (unsigned short*)(ws + ((size_t)20<<20));               // 128 KB
  float*          bsum  = (float*)(ws + ((size_t)20<<20) + (128<<10));  // 4 KB
  unsigned short* wc0bf = (unsigned short*)(ws + ((size_t)20<<20) + (132<<10)); // 288 KB
  unsigned short* wc1bf = (unsigned short*)(ws + ((size_t)20<<20) + (420<<10)); // 288 KB

  k_prep<<<1410,256,0,stream>>>(W_h0, W_c0, W_hh, b_ih, b_hh, wc0bf, wc1bf, whhbf, bsum);
  k_hid<<<NPX/2,256,0,stream>>>(mp, gl, W_hid, b_hid, hidbf);
  k_conv_mfma<<<BB*MM,256,0,stream>>>(hidbf, wc0bf, b_h0, (float*)nullptr, hbfA);
  k_conv_mfma<<<BB*MM,256,0,stream>>>(hidbf, wc1bf, b_c0, cbuf, (unsigned short*)nullptr);

  unsigned short* hc = hbfA; unsigned short* hn = hbfB;
  for (int s=0;s<NSTEPS;s++){
    k_step<<<BB*MM,256,0,stream>>>(hc, whhbf, W_f, b_f, W_ih, bsum, cbuf, hn);
    unsigned short* tmp = hc; hc = hn; hn = tmp;
  }
  k_policy<<<NPX/4,256,0,stream>>>(hc, W_pol, out);
}